// Round 8
// baseline (175.706 us; speedup 1.0000x reference)
//
#include <hip/hip_runtime.h>
#include <hip/hip_bf16.h>

typedef _Float16 f16x8 __attribute__((ext_vector_type(8)));
typedef _Float16 h2 __attribute__((ext_vector_type(2)));
typedef float f32x4 __attribute__((ext_vector_type(4)));
typedef unsigned int u32x2 __attribute__((ext_vector_type(2)));
typedef unsigned short us8 __attribute__((ext_vector_type(8)));

#define GLDS16(gp, lp)                                                        \
  __builtin_amdgcn_global_load_lds(                                           \
      (const __attribute__((address_space(1))) void*)(gp),                    \
      (__attribute__((address_space(3))) void*)(lp), 16, 0, 0)

__device__ __forceinline__ unsigned short f2h(float f) {
  _Float16 h = (_Float16)f;
  return __builtin_bit_cast(unsigned short, h);
}
__device__ __forceinline__ float h2f(unsigned short u) {
  return (float)__builtin_bit_cast(_Float16, u);
}

// ---------------- K1a: convert key0/value0/query0 f32 -> f16 ----------------
__global__ __launch_bounds__(256) void k_convert_in(
    const float* __restrict__ k0, const float* __restrict__ v0,
    const float* __restrict__ q0, unsigned short* __restrict__ dst) {
  const float* src = blockIdx.y == 0 ? k0 : (blockIdx.y == 1 ? v0 : q0);
  unsigned short* d = dst + (size_t)blockIdx.y * 4194304u;
  const float4* s4 = (const float4*)src;
  ushort4* d4 = (ushort4*)d;
  for (int i = blockIdx.x * 256 + threadIdx.x; i < 1048576; i += 1024 * 256) {
    float4 f = s4[i];
    ushort4 o;
    o.x = f2h(f.x); o.y = f2h(f.y); o.z = f2h(f.z); o.w = f2h(f.w);
    d4[i] = o;
  }
}

// ------------- K1b: weights f32 [256][512] -> f16 transposed [512][256] -----
__global__ __launch_bounds__(256) void k_convert_w(
    const float* __restrict__ Wk, const float* __restrict__ Wv,
    const float* __restrict__ Wq, const float* __restrict__ Wr,
    unsigned short* __restrict__ WT) {
  int o = blockIdx.x * 256 + threadIdx.x;  // 0..524287
  int mat = o >> 17, rem = o & 131071;
  int n = rem >> 8, k = rem & 255;
  const float* W = mat == 0 ? Wk : mat == 1 ? Wv : mat == 2 ? Wq : Wr;
  WT[o] = f2h(W[k * 512 + n]);
}

// ---------------- K2: 4 projection GEMMs, f16 MFMA ----------------
// C[16384,512] = A[16384,256] * W[256,512] + bias ; mat: 0=K,1=V,2=Q(scaled),3=R
// 1-D grid, XCD-bijective: the 4 n-tiles of one (m,mat) panel share an XCD.
__global__ __launch_bounds__(256) void k_gemm(
    const unsigned short* __restrict__ Ab, const unsigned short* __restrict__ WT,
    const float* __restrict__ bk, const float* __restrict__ bv,
    const float* __restrict__ bq, const float* __restrict__ br,
    unsigned short* __restrict__ Kb, unsigned short* __restrict__ Vh,
    unsigned short* __restrict__ Qb, unsigned short* __restrict__ Rh) {
  const float CS = 0.70710678118654752f * 1.44269504088896341f;
  int b = blockIdx.x;
  int id2 = (b & 7) * 256 + (b >> 3);       // XCD c owns id2 in [c*256,(c+1)*256)
  int nx = id2 & 3, my = (id2 >> 2) & 127, mat = id2 >> 9;
  const unsigned short* A = Ab + (size_t)(mat == 3 ? 2 : mat) * 4194304u;
  const unsigned short* Wm = WT + mat * 131072;
  const float* bias = mat == 0 ? bk : mat == 1 ? bv : mat == 2 ? bq : br;
  unsigned short* C = mat == 0 ? Kb : mat == 1 ? Vh : mat == 2 ? Qb : Rh;
  __shared__ unsigned short As[4096];  // [128][32]
  __shared__ unsigned short Bs[4096];  // [128 n][32 k]  (W^T tile)
  int m0 = my * 128, n0 = nx * 128;
  int tid = threadIdx.x, lane = tid & 63, w = tid >> 6;
  int wm = w >> 1, wn = w & 1, q = lane & 15, hi = lane >> 4;
  f32x4 acc[4][4];
#pragma unroll
  for (int i = 0; i < 4; ++i)
#pragma unroll
    for (int j = 0; j < 4; ++j) acc[i][j] = f32x4{0.f, 0.f, 0.f, 0.f};

  const unsigned short* gA = A + (m0 + (tid >> 2)) * 256 + (tid & 3) * 8;
  const unsigned short* gB = Wm + (n0 + (tid >> 2)) * 256 + (tid & 3) * 8;

  for (int kt = 0; kt < 8; ++kt) {
    __syncthreads();
    GLDS16(gA, &As[tid * 8]);
    GLDS16(gA + 64 * 256, &As[2048 + tid * 8]);
    GLDS16(gB, &Bs[tid * 8]);
    GLDS16(gB + 64 * 256, &Bs[2048 + tid * 8]);
    gA += 32; gB += 32;
    __syncthreads();
    f16x8 af[4], bf[4];
#pragma unroll
    for (int i = 0; i < 4; ++i)
      af[i] = *(const f16x8*)&As[(wm * 64 + i * 16 + q) * 32 + hi * 8];
#pragma unroll
    for (int j = 0; j < 4; ++j)
      bf[j] = *(const f16x8*)&Bs[(wn * 64 + j * 16 + q) * 32 + hi * 8];
#pragma unroll
    for (int i = 0; i < 4; ++i)
#pragma unroll
      for (int j = 0; j < 4; ++j)
        acc[i][j] = __builtin_amdgcn_mfma_f32_16x16x32_f16(af[i], bf[j], acc[i][j], 0, 0, 0);
  }

  float scale = (mat == 2) ? CS : 1.0f;
#pragma unroll
  for (int j = 0; j < 4; ++j) {
    int col = n0 + wn * 64 + j * 16 + q;
    float bs = bias[col];
#pragma unroll
    for (int i = 0; i < 4; ++i) {
      int rb = m0 + wm * 64 + i * 16 + 4 * hi;
#pragma unroll
      for (int r = 0; r < 4; ++r) {
        float v = (acc[i][j][r] + bs) * scale;
        C[(rb + r) * 512 + col] = f2h(v);
      }
    }
  }
}

// -------- K2b: V transpose per group: Vt[g][d][s] = Vh(flat)[g][s][d] -------
__global__ __launch_bounds__(256) void k_vt(
    const unsigned short* __restrict__ Vh, unsigned short* __restrict__ Vt) {
  int t0 = blockIdx.x * 256 + threadIdx.x;  // 0..524287
#pragma unroll
  for (int it = 0; it < 2; ++it) {
    int c = t0 + it * 524288;  // chunk id 0..1048575 : 8 shorts each
    int s8 = c & 127, d = (c >> 7) & 31, g = c >> 12;  // g in [0,256)
    const unsigned short* src = Vh + g * 32768 + s8 * 256 + d;
    us8 v;
#pragma unroll
    for (int i = 0; i < 8; ++i) v[i] = src[i * 32];
    *(us8*)&Vt[g * 32768 + d * 1024 + s8 * 8] = v;
  }
}

// ---------------- K3: attention + residual + relu ----------------
// Static-shift softmax via MFMA C-init: st = K^T Q + (-24); p = exp2(st).
// l via fdot2 accumulation (cross-lane reduced once at end).
// Deferred-read pipeline: both qt write-phases before both read/PV-phases,
// so the LDS write->read latency hides under the other qt's QK/exp.
__global__ __launch_bounds__(256, 4) void k_attn(
    const unsigned short* __restrict__ Kb, const unsigned short* __restrict__ Vt,
    const unsigned short* __restrict__ Qb, const unsigned short* __restrict__ Rh,
    float* __restrict__ out) {
  int p = blockIdx.x;
  int g = (p & 7) + 8 * (p >> 6);   // XCD-bijective: a group's 8 blocks share an XCD
  int sub = (p >> 3) & 7;
  int tid = threadIdx.x, lane = tid & 63, wid = tid >> 6;
  int q = lane & 15, hi = lane >> 4;
  int slice = sub * 4 + wid;        // 0..31 : 32 q-rows per wave
  const unsigned short* Qg = Qb + g * 32768 + slice * 1024;
  const unsigned short* Kg = Kb + g * 32768;
  const unsigned short* Vg = Vt + g * 32768;  // [32 d][1024 s]
  __shared__ __align__(16) unsigned short Pl[8][1024];  // [wave*2+qt][16 q][64]
  int swz = (q & 7) << 4;
  char* pq0 = (char*)&Pl[wid * 2 + 0][0] + q * 128;
  char* pq1 = (char*)&Pl[wid * 2 + 1][0] + q * 128;
  int w0 = (hi * 8) ^ swz;    // write: ^ t*32
  int r0 = (hi * 16) ^ swz;   // read:  ^ c*64

  f16x8 qf[2];
#pragma unroll
  for (int t = 0; t < 2; ++t)
    qf[t] = *(const f16x8*)&Qg[(t * 16 + q) * 32 + hi * 8];

  const h2 ones2 = {(_Float16)1.0f, (_Float16)1.0f};

  f32x4 o[2][2];
#pragma unroll
  for (int a = 0; a < 2; ++a)
#pragma unroll
    for (int b2 = 0; b2 < 2; ++b2) o[a][b2] = f32x4{0.f, 0.f, 0.f, 0.f};
  float lacc[2] = {0.f, 0.f};
  const f32x4 neg24 = {-24.f, -24.f, -24.f, -24.f};

  const unsigned short* Kl = Kg + q * 32 + hi * 8;
  const unsigned short* Vl = Vg + q * 1024 + hi * 8;

  // K prefetch: kf holds tile kv, loaded one iteration ahead
  f16x8 kf[4];
#pragma unroll
  for (int t = 0; t < 4; ++t)
    kf[t] = *(const f16x8*)(Kl + t * 512);

  for (int kv = 0; kv < 16; ++kv) {
    int nx = (kv + 1) & 15;  // wraps on last iter (harmless reload of tile 0)
    f16x8 nkf[4];
#pragma unroll
    for (int t = 0; t < 4; ++t)
      nkf[t] = *(const f16x8*)(Kl + nx * 2048 + t * 512);
    f16x8 vf[2][2];
#pragma unroll
    for (int dt = 0; dt < 2; ++dt)
#pragma unroll
      for (int c = 0; c < 2; ++c)
        vf[dt][c] = *(const f16x8*)(Vl + dt * 16384 + kv * 64 + c * 32);

    // ---- front half qt=0: QK, exp, pack, write, l-dot ----
    f32x4 st0[4];
    __builtin_amdgcn_s_setprio(1);
#pragma unroll
    for (int t = 0; t < 4; ++t)
      st0[t] = __builtin_amdgcn_mfma_f32_16x16x32_f16(kf[t], qf[0], neg24, 0, 0, 0);
    __builtin_amdgcn_s_setprio(0);
    unsigned int pp0[8];
#pragma unroll
    for (int t = 0; t < 4; ++t) {
      float p0 = __builtin_amdgcn_exp2f(st0[t][0]);
      float p1 = __builtin_amdgcn_exp2f(st0[t][1]);
      float p2 = __builtin_amdgcn_exp2f(st0[t][2]);
      float p3 = __builtin_amdgcn_exp2f(st0[t][3]);
      pp0[2 * t] = __builtin_bit_cast(unsigned int, __builtin_amdgcn_cvt_pkrtz(p0, p1));
      pp0[2 * t + 1] = __builtin_bit_cast(unsigned int, __builtin_amdgcn_cvt_pkrtz(p2, p3));
    }
#pragma unroll
    for (int t = 0; t < 4; ++t)
      *(u32x2*)(pq0 + (w0 ^ (t * 32))) = u32x2{pp0[2 * t], pp0[2 * t + 1]};
#pragma unroll
    for (int i = 0; i < 8; ++i)
      lacc[0] = __builtin_amdgcn_fdot2(__builtin_bit_cast(h2, pp0[i]), ones2, lacc[0], false);

    // ---- front half qt=1 ----
    f32x4 st1[4];
    __builtin_amdgcn_s_setprio(1);
#pragma unroll
    for (int t = 0; t < 4; ++t)
      st1[t] = __builtin_amdgcn_mfma_f32_16x16x32_f16(kf[t], qf[1], neg24, 0, 0, 0);
    __builtin_amdgcn_s_setprio(0);
    unsigned int pp1[8];
#pragma unroll
    for (int t = 0; t < 4; ++t) {
      float p0 = __builtin_amdgcn_exp2f(st1[t][0]);
      float p1 = __builtin_amdgcn_exp2f(st1[t][1]);
      float p2 = __builtin_amdgcn_exp2f(st1[t][2]);
      float p3 = __builtin_amdgcn_exp2f(st1[t][3]);
      pp1[2 * t] = __builtin_bit_cast(unsigned int, __builtin_amdgcn_cvt_pkrtz(p0, p1));
      pp1[2 * t + 1] = __builtin_bit_cast(unsigned int, __builtin_amdgcn_cvt_pkrtz(p2, p3));
    }
#pragma unroll
    for (int t = 0; t < 4; ++t)
      *(u32x2*)(pq1 + (w0 ^ (t * 32))) = u32x2{pp1[2 * t], pp1[2 * t + 1]};
#pragma unroll
    for (int i = 0; i < 8; ++i)
      lacc[1] = __builtin_amdgcn_fdot2(__builtin_bit_cast(h2, pp1[i]), ones2, lacc[1], false);

    // ---- back half: reads + PV (cross-lane RAW fence first) ----
    __builtin_amdgcn_wave_barrier();
    {
      f16x8 pf0 = *(const f16x8*)(pq0 + r0);
      f16x8 pf1 = *(const f16x8*)(pq0 + (r0 ^ 64));
      __builtin_amdgcn_s_setprio(1);
      o[0][0] = __builtin_amdgcn_mfma_f32_16x16x32_f16(vf[0][0], pf0, o[0][0], 0, 0, 0);
      o[0][1] = __builtin_amdgcn_mfma_f32_16x16x32_f16(vf[1][0], pf0, o[0][1], 0, 0, 0);
      o[0][0] = __builtin_amdgcn_mfma_f32_16x16x32_f16(vf[0][1], pf1, o[0][0], 0, 0, 0);
      o[0][1] = __builtin_amdgcn_mfma_f32_16x16x32_f16(vf[1][1], pf1, o[0][1], 0, 0, 0);
      __builtin_amdgcn_s_setprio(0);
    }
    {
      f16x8 pf0 = *(const f16x8*)(pq1 + r0);
      f16x8 pf1 = *(const f16x8*)(pq1 + (r0 ^ 64));
      __builtin_amdgcn_s_setprio(1);
      o[1][0] = __builtin_amdgcn_mfma_f32_16x16x32_f16(vf[0][0], pf0, o[1][0], 0, 0, 0);
      o[1][1] = __builtin_amdgcn_mfma_f32_16x16x32_f16(vf[1][0], pf0, o[1][1], 0, 0, 0);
      o[1][0] = __builtin_amdgcn_mfma_f32_16x16x32_f16(vf[0][1], pf1, o[1][0], 0, 0, 0);
      o[1][1] = __builtin_amdgcn_mfma_f32_16x16x32_f16(vf[1][1], pf1, o[1][1], 0, 0, 0);
      __builtin_amdgcn_s_setprio(0);
    }
    __builtin_amdgcn_wave_barrier();  // WAR fence vs next iter's writes
#pragma unroll
    for (int t = 0; t < 4; ++t) kf[t] = nkf[t];
  }

  // final cross-lane l reduction (per qt): sum the 4 hi-groups
#pragma unroll
  for (int qt = 0; qt < 2; ++qt) {
    lacc[qt] += __shfl_xor(lacc[qt], 16, 64);
    lacc[qt] += __shfl_xor(lacc[qt], 32, 64);
  }

#pragma unroll
  for (int qt = 0; qt < 2; ++qt) {
    float iv = 1.0f / lacc[qt];
#pragma unroll
    for (int dt = 0; dt < 2; ++dt) {
      int off = g * 32768 + (slice * 32 + qt * 16 + q) * 32 + dt * 16 + hi * 4;
      ushort4 rr = *(const ushort4*)&Rh[off];
      f32x4 a = o[qt][dt];
      float4 ov;
      ov.x = fmaxf(h2f(rr.x) + a[0] * iv, 0.f);
      ov.y = fmaxf(h2f(rr.y) + a[1] * iv, 0.f);
      ov.z = fmaxf(h2f(rr.z) + a[2] * iv, 0.f);
      ov.w = fmaxf(h2f(rr.w) + a[3] * iv, 0.f);
      *(float4*)&out[off] = ov;
    }
  }
}

extern "C" void kernel_launch(void* const* d_in, const int* in_sizes, int n_in,
                              void* d_out, int out_size, void* d_ws, size_t ws_size,
                              hipStream_t stream) {
  const float* key0 = (const float*)d_in[0];
  const float* value0 = (const float*)d_in[1];
  const float* query0 = (const float*)d_in[2];
  const float* Wk = (const float*)d_in[3];
  const float* bk = (const float*)d_in[4];
  const float* Wv = (const float*)d_in[5];
  const float* bv = (const float*)d_in[6];
  const float* Wq = (const float*)d_in[7];
  const float* bq = (const float*)d_in[8];
  const float* Wr = (const float*)d_in[9];
  const float* br = (const float*)d_in[10];
  float* out = (float*)d_out;
  char* ws = (char*)d_ws;
  unsigned short* Kb = (unsigned short*)(ws);              // 16 MB f16 [16384,512]
  unsigned short* Vt = (unsigned short*)(ws + 16777216);   // 16 MB f16 [256][32][1024]
  unsigned short* Qb = (unsigned short*)(ws + 33554432);   // 16 MB f16 (pre-scaled)
  unsigned short* Rh = (unsigned short*)(ws + 50331648);   // 16 MB f16 [16384,512]
  unsigned short* Ab = (unsigned short*)(ws + 67108864);   // 24 MB f16 [3][16384,256]
  unsigned short* WT = (unsigned short*)(ws + 92274688);   // 1 MB f16 [4][512][256]
  unsigned short* Vh = (unsigned short*)(ws + 93323264);   // 16 MB f16 [16384,512]

  k_convert_in<<<dim3(1024, 3), dim3(256), 0, stream>>>(key0, value0, query0, Ab);
  k_convert_w<<<dim3(2048), dim3(256), 0, stream>>>(Wk, Wv, Wq, Wr, WT);
  k_gemm<<<dim3(2048), dim3(256), 0, stream>>>(Ab, WT, bk, bv, bq, br, Kb, Vh, Qb, Rh);
  k_vt<<<dim3(2048), dim3(256), 0, stream>>>(Vh, Vt);
  k_attn<<<dim3(2048), dim3(256), 0, stream>>>(Kb, Vt, Qb, Rh, out);
}

// Round 10
// 142.180 us; speedup vs baseline: 1.2358x; 1.2358x over previous
//
#include <hip/hip_runtime.h>
#include <hip/hip_bf16.h>

typedef _Float16 f16x8 __attribute__((ext_vector_type(8)));
typedef _Float16 h2 __attribute__((ext_vector_type(2)));
typedef float f32x4 __attribute__((ext_vector_type(4)));
typedef unsigned int u32x2 __attribute__((ext_vector_type(2)));
typedef unsigned short us8 __attribute__((ext_vector_type(8)));

#define GLDS16(gp, lp)                                                        \
  __builtin_amdgcn_global_load_lds(                                           \
      (const __attribute__((address_space(1))) void*)(gp),                    \
      (__attribute__((address_space(3))) void*)(lp), 16, 0, 0)

__device__ __forceinline__ unsigned short f2h(float f) {
  _Float16 h = (_Float16)f;
  return __builtin_bit_cast(unsigned short, h);
}
__device__ __forceinline__ float h2f(unsigned short u) {
  return (float)__builtin_bit_cast(_Float16, u);
}

// ---------------- K1a: convert key0/value0/query0 f32 -> f16 ----------------
__global__ __launch_bounds__(256) void k_convert_in(
    const float* __restrict__ k0, const float* __restrict__ v0,
    const float* __restrict__ q0, unsigned short* __restrict__ dst) {
  const float* src = blockIdx.y == 0 ? k0 : (blockIdx.y == 1 ? v0 : q0);
  unsigned short* d = dst + (size_t)blockIdx.y * 4194304u;
  const float4* s4 = (const float4*)src;
  ushort4* d4 = (ushort4*)d;
  for (int i = blockIdx.x * 256 + threadIdx.x; i < 1048576; i += 1024 * 256) {
    float4 f = s4[i];
    ushort4 o;
    o.x = f2h(f.x); o.y = f2h(f.y); o.z = f2h(f.z); o.w = f2h(f.w);
    d4[i] = o;
  }
}

// ------------- K1b: weights f32 [256][512] -> f16 transposed [512][256] -----
__global__ __launch_bounds__(256) void k_convert_w(
    const float* __restrict__ Wk, const float* __restrict__ Wv,
    const float* __restrict__ Wq, const float* __restrict__ Wr,
    unsigned short* __restrict__ WT) {
  int o = blockIdx.x * 256 + threadIdx.x;  // 0..524287
  int mat = o >> 17, rem = o & 131071;
  int n = rem >> 8, k = rem & 255;
  const float* W = mat == 0 ? Wk : mat == 1 ? Wv : mat == 2 ? Wq : Wr;
  WT[o] = f2h(W[k * 512 + n]);
}

// ---------------- K2: 4 projection GEMMs, f16 MFMA ----------------
__global__ __launch_bounds__(256) void k_gemm(
    const unsigned short* __restrict__ Ab, const unsigned short* __restrict__ WT,
    const float* __restrict__ bk, const float* __restrict__ bv,
    const float* __restrict__ bq, const float* __restrict__ br,
    unsigned short* __restrict__ Kb, unsigned short* __restrict__ Vh,
    unsigned short* __restrict__ Qb, unsigned short* __restrict__ Rh) {
  const float CS = 0.70710678118654752f * 1.44269504088896341f;
  int b = blockIdx.x;
  int id2 = (b & 7) * 256 + (b >> 3);       // XCD c owns id2 in [c*256,(c+1)*256)
  int nx = id2 & 3, my = (id2 >> 2) & 127, mat = id2 >> 9;
  const unsigned short* A = Ab + (size_t)(mat == 3 ? 2 : mat) * 4194304u;
  const unsigned short* Wm = WT + mat * 131072;
  const float* bias = mat == 0 ? bk : mat == 1 ? bv : mat == 2 ? bq : br;
  unsigned short* C = mat == 0 ? Kb : mat == 1 ? Vh : mat == 2 ? Qb : Rh;
  __shared__ unsigned short As[4096];  // [128][32]
  __shared__ unsigned short Bs[4096];  // [128 n][32 k]
  int m0 = my * 128, n0 = nx * 128;
  int tid = threadIdx.x, lane = tid & 63, w = tid >> 6;
  int wm = w >> 1, wn = w & 1, q = lane & 15, hi = lane >> 4;
  f32x4 acc[4][4];
#pragma unroll
  for (int i = 0; i < 4; ++i)
#pragma unroll
    for (int j = 0; j < 4; ++j) acc[i][j] = f32x4{0.f, 0.f, 0.f, 0.f};

  const unsigned short* gA = A + (m0 + (tid >> 2)) * 256 + (tid & 3) * 8;
  const unsigned short* gB = Wm + (n0 + (tid >> 2)) * 256 + (tid & 3) * 8;

  for (int kt = 0; kt < 8; ++kt) {
    __syncthreads();
    GLDS16(gA, &As[tid * 8]);
    GLDS16(gA + 64 * 256, &As[2048 + tid * 8]);
    GLDS16(gB, &Bs[tid * 8]);
    GLDS16(gB + 64 * 256, &Bs[2048 + tid * 8]);
    gA += 32; gB += 32;
    __syncthreads();
    f16x8 af[4], bf[4];
#pragma unroll
    for (int i = 0; i < 4; ++i)
      af[i] = *(const f16x8*)&As[(wm * 64 + i * 16 + q) * 32 + hi * 8];
#pragma unroll
    for (int j = 0; j < 4; ++j)
      bf[j] = *(const f16x8*)&Bs[(wn * 64 + j * 16 + q) * 32 + hi * 8];
#pragma unroll
    for (int i = 0; i < 4; ++i)
#pragma unroll
      for (int j = 0; j < 4; ++j)
        acc[i][j] = __builtin_amdgcn_mfma_f32_16x16x32_f16(af[i], bf[j], acc[i][j], 0, 0, 0);
  }

  float scale = (mat == 2) ? CS : 1.0f;
#pragma unroll
  for (int j = 0; j < 4; ++j) {
    int col = n0 + wn * 64 + j * 16 + q;
    float bs = bias[col];
#pragma unroll
    for (int i = 0; i < 4; ++i) {
      int rb = m0 + wm * 64 + i * 16 + 4 * hi;
#pragma unroll
      for (int r = 0; r < 4; ++r) {
        float v = (acc[i][j][r] + bs) * scale;
        C[(rb + r) * 512 + col] = f2h(v);
      }
    }
  }
}

// -------- K2b: V transpose per group: Vt[g][d][s] = Vh(flat)[g][s][d] -------
__global__ __launch_bounds__(256) void k_vt(
    const unsigned short* __restrict__ Vh, unsigned short* __restrict__ Vt) {
  int t0 = blockIdx.x * 256 + threadIdx.x;  // 0..524287
#pragma unroll
  for (int it = 0; it < 2; ++it) {
    int c = t0 + it * 524288;  // chunk id 0..1048575 : 8 shorts each
    int s8 = c & 127, d = (c >> 7) & 31, g = c >> 12;  // g in [0,256)
    const unsigned short* src = Vh + g * 32768 + s8 * 256 + d;
    us8 v;
#pragma unroll
    for (int i = 0; i < 8; ++i) v[i] = src[i * 32];
    *(us8*)&Vt[g * 32768 + d * 1024 + s8 * 8] = v;
  }
}

// ---------------- K3: attention + residual + relu ----------------
// K+V staged once per block into LDS (XOR-swizzled via pre-swizzled global
// source); 8 waves x 64 q-rows consume from LDS -- no global loads in the
// kv loop. Static-shift softmax (MFMA C-init -24), l via fdot2.
// Swizzle algebra: LDS[d] = G[d ^ f(d)] with f bits disjoint from XOR bits;
// reads at addr a use d = a ^ f(a). Terms overlapping the XOR window (c*64
// on the V path, bit 6) MUST be XOR-composed, not added (R9 bug).
__global__ __launch_bounds__(512, 2) void k_attn(
    const unsigned short* __restrict__ Kb, const unsigned short* __restrict__ Vt,
    const unsigned short* __restrict__ Qb, const unsigned short* __restrict__ Rh,
    float* __restrict__ out) {
  __shared__ __align__(16) char Ks[65536];           // [1024 s][32 d] swizzled
  __shared__ __align__(16) char Vs[65536];           // [32 d][1024 s] swizzled
  __shared__ __align__(16) unsigned short Pl[8][1024];  // per-wave P scratch

  int p = blockIdx.x;                  // 512 blocks
  int id = (p & 7) * 64 + (p >> 3);    // XCD-bijective; ids 2g,2g+1 same XCD
  int g = id >> 1, sub = id & 1;
  int tid = threadIdx.x, lane = tid & 63, wid = tid >> 6;
  int q = lane & 15, hi = lane >> 4;
  int slice = sub * 8 + wid;           // 0..15 : this wave's 64 q-rows

  // ---- stage K and V (64KB each) with inverse-swizzled global source ----
  const char* Ksrc = (const char*)Kb + (size_t)g * 65536;
  const char* Vsrc = (const char*)Vt + (size_t)g * 65536;
#pragma unroll
  for (int r = 0; r < 8; ++r) {
    int d = tid * 16 + r * 8192;
    GLDS16(Ksrc + (d ^ (((d >> 7) & 7) << 4)), Ks + d);
    GLDS16(Vsrc + (d ^ (((d >> 11) & 7) << 4)), Vs + d);
  }

  // Q fragments (global, overlap staging latency)
  const unsigned short* Qg = Qb + g * 32768 + slice * 2048;
  f16x8 qf[4];
#pragma unroll
  for (int t = 0; t < 4; ++t)
    qf[t] = *(const f16x8*)&Qg[(t * 16 + q) * 32 + hi * 8];

  // P-scratch addressing (same as proven R4 scheme)
  int swz = (q & 7) << 4;
  char* pq = (char*)&Pl[wid][0] + q * 128;
  int w0 = (hi * 8) ^ swz;    // write: ^ t*32
  int r0 = (hi * 16) ^ swz;   // read:  ^ c*64

  // LDS read bases (swizzle folded in; XOR window = bits 4-6)
  int kbase = (q * 64 + hi * 16) ^ (((q >> 1) & 7) << 4);   // + kv*4096 + t*1024 (bits>=10: safe to add)
  int vbase = (q * 2048 + hi * 16) ^ ((q & 7) << 4);        // + dt*32768 + kv*128 (bits>=7: safe); ^ c*64 (bit 6!)

  const h2 ones2 = {(_Float16)1.0f, (_Float16)1.0f};
  f32x4 o[4][2];
#pragma unroll
  for (int a = 0; a < 4; ++a)
#pragma unroll
    for (int b2 = 0; b2 < 2; ++b2) o[a][b2] = f32x4{0.f, 0.f, 0.f, 0.f};
  float lacc[4] = {0.f, 0.f, 0.f, 0.f};
  const f32x4 neg24 = {-24.f, -24.f, -24.f, -24.f};

  __syncthreads();  // staging complete (drains vmcnt)

  for (int kv = 0; kv < 16; ++kv) {
    f16x8 kf[4];
#pragma unroll
    for (int t = 0; t < 4; ++t)
      kf[t] = *(const f16x8*)(Ks + kbase + kv * 4096 + t * 1024);
    f16x8 vf[2][2];
#pragma unroll
    for (int dt = 0; dt < 2; ++dt)
#pragma unroll
      for (int c = 0; c < 2; ++c)
        vf[dt][c] = *(const f16x8*)(Vs + ((vbase + dt * 32768 + kv * 128) ^ (c * 64)));

#pragma unroll
    for (int qt = 0; qt < 4; ++qt) {
      f32x4 st[4];
      __builtin_amdgcn_s_setprio(1);
#pragma unroll
      for (int t = 0; t < 4; ++t)
        st[t] = __builtin_amdgcn_mfma_f32_16x16x32_f16(kf[t], qf[qt], neg24, 0, 0, 0);
      __builtin_amdgcn_s_setprio(0);

      unsigned int pp[8];
#pragma unroll
      for (int t = 0; t < 4; ++t) {
        float p0 = __builtin_amdgcn_exp2f(st[t][0]);
        float p1 = __builtin_amdgcn_exp2f(st[t][1]);
        float p2 = __builtin_amdgcn_exp2f(st[t][2]);
        float p3 = __builtin_amdgcn_exp2f(st[t][3]);
        pp[2 * t] = __builtin_bit_cast(unsigned int, __builtin_amdgcn_cvt_pkrtz(p0, p1));
        pp[2 * t + 1] = __builtin_bit_cast(unsigned int, __builtin_amdgcn_cvt_pkrtz(p2, p3));
      }

#pragma unroll
      for (int t = 0; t < 4; ++t)
        *(u32x2*)(pq + (w0 ^ (t * 32))) = u32x2{pp[2 * t], pp[2 * t + 1]};
#pragma unroll
      for (int i = 0; i < 8; ++i)
        lacc[qt] = __builtin_amdgcn_fdot2(__builtin_bit_cast(h2, pp[i]), ones2, lacc[qt], false);

      __builtin_amdgcn_wave_barrier();
      f16x8 pf0 = *(const f16x8*)(pq + r0);
      f16x8 pf1 = *(const f16x8*)(pq + (r0 ^ 64));
      __builtin_amdgcn_s_setprio(1);
      o[qt][0] = __builtin_amdgcn_mfma_f32_16x16x32_f16(vf[0][0], pf0, o[qt][0], 0, 0, 0);
      o[qt][1] = __builtin_amdgcn_mfma_f32_16x16x32_f16(vf[1][0], pf0, o[qt][1], 0, 0, 0);
      o[qt][0] = __builtin_amdgcn_mfma_f32_16x16x32_f16(vf[0][1], pf1, o[qt][0], 0, 0, 0);
      o[qt][1] = __builtin_amdgcn_mfma_f32_16x16x32_f16(vf[1][1], pf1, o[qt][1], 0, 0, 0);
      __builtin_amdgcn_s_setprio(0);
      __builtin_amdgcn_wave_barrier();  // WAR fence before next qt's writes
    }
  }

  // final cross-lane l reduction (per qt)
#pragma unroll
  for (int qt = 0; qt < 4; ++qt) {
    lacc[qt] += __shfl_xor(lacc[qt], 16, 64);
    lacc[qt] += __shfl_xor(lacc[qt], 32, 64);
  }

#pragma unroll
  for (int qt = 0; qt < 4; ++qt) {
    float iv = 1.0f / lacc[qt];
#pragma unroll
    for (int dt = 0; dt < 2; ++dt) {
      int off = g * 32768 + (slice * 64 + qt * 16 + q) * 32 + dt * 16 + hi * 4;
      ushort4 rr = *(const ushort4*)&Rh[off];
      f32x4 a = o[qt][dt];
      float4 ov;
      ov.x = fmaxf(h2f(rr.x) + a[0] * iv, 0.f);
      ov.y = fmaxf(h2f(rr.y) + a[1] * iv, 0.f);
      ov.z = fmaxf(h2f(rr.z) + a[2] * iv, 0.f);
      ov.w = fmaxf(h2f(rr.w) + a[3] * iv, 0.f);
      *(float4*)&out[off] = ov;
    }
  }
}

extern "C" void kernel_launch(void* const* d_in, const int* in_sizes, int n_in,
                              void* d_out, int out_size, void* d_ws, size_t ws_size,
                              hipStream_t stream) {
  const float* key0 = (const float*)d_in[0];
  const float* value0 = (const float*)d_in[1];
  const float* query0 = (const float*)d_in[2];
  const float* Wk = (const float*)d_in[3];
  const float* bk = (const float*)d_in[4];
  const float* Wv = (const float*)d_in[5];
  const float* bv = (const float*)d_in[6];
  const float* Wq = (const float*)d_in[7];
  const float* bq = (const float*)d_in[8];
  const float* Wr = (const float*)d_in[9];
  const float* br = (const float*)d_in[10];
  float* out = (float*)d_out;
  char* ws = (char*)d_ws;
  unsigned short* Kb = (unsigned short*)(ws);              // 16 MB f16 [16384,512]
  unsigned short* Vt = (unsigned short*)(ws + 16777216);   // 16 MB f16 [256][32][1024]
  unsigned short* Qb = (unsigned short*)(ws + 33554432);   // 16 MB f16 (pre-scaled)
  unsigned short* Rh = (unsigned short*)(ws + 50331648);   // 16 MB f16 [16384,512]
  unsigned short* Ab = (unsigned short*)(ws + 67108864);   // 24 MB f16 [3][16384,256]
  unsigned short* WT = (unsigned short*)(ws + 92274688);   // 1 MB f16 [4][512][256]
  unsigned short* Vh = (unsigned short*)(ws + 93323264);   // 16 MB f16 [16384,512]

  k_convert_in<<<dim3(1024, 3), dim3(256), 0, stream>>>(key0, value0, query0, Ab);
  k_convert_w<<<dim3(2048), dim3(256), 0, stream>>>(Wk, Wv, Wq, Wr, WT);
  k_gemm<<<dim3(2048), dim3(256), 0, stream>>>(Ab, WT, bk, bv, bq, br, Kb, Vh, Qb, Rh);
  k_vt<<<dim3(2048), dim3(256), 0, stream>>>(Vh, Vt);
  k_attn<<<dim3(512), dim3(512), 0, stream>>>(Kb, Vt, Qb, Rh, out);
}

// Round 12
// 135.596 us; speedup vs baseline: 1.2958x; 1.0486x over previous
//
#include <hip/hip_runtime.h>
#include <hip/hip_bf16.h>

typedef _Float16 f16x8 __attribute__((ext_vector_type(8)));
typedef _Float16 f16x2 __attribute__((ext_vector_type(2)));
typedef float f32x4 __attribute__((ext_vector_type(4)));
typedef float f32x16 __attribute__((ext_vector_type(16)));
typedef unsigned int u32x4 __attribute__((ext_vector_type(4)));
typedef unsigned short us8 __attribute__((ext_vector_type(8)));

#define GLDS16(gp, lp)                                                        \
  __builtin_amdgcn_global_load_lds(                                           \
      (const __attribute__((address_space(1))) void*)(gp),                    \
      (__attribute__((address_space(3))) void*)(lp), 16, 0, 0)

__device__ __forceinline__ unsigned short f2h(float f) {
  _Float16 h = (_Float16)f;
  return __builtin_bit_cast(unsigned short, h);
}
__device__ __forceinline__ float h2f(unsigned short u) {
  return (float)__builtin_bit_cast(_Float16, u);
}

// ---------------- K1a: convert key0/value0/query0 f32 -> f16 ----------------
__global__ __launch_bounds__(256) void k_convert_in(
    const float* __restrict__ k0, const float* __restrict__ v0,
    const float* __restrict__ q0, unsigned short* __restrict__ dst) {
  const float* src = blockIdx.y == 0 ? k0 : (blockIdx.y == 1 ? v0 : q0);
  unsigned short* d = dst + (size_t)blockIdx.y * 4194304u;
  const float4* s4 = (const float4*)src;
  ushort4* d4 = (ushort4*)d;
  for (int i = blockIdx.x * 256 + threadIdx.x; i < 1048576; i += 1024 * 256) {
    float4 f = s4[i];
    ushort4 o;
    o.x = f2h(f.x); o.y = f2h(f.y); o.z = f2h(f.z); o.w = f2h(f.w);
    d4[i] = o;
  }
}

// ------------- K1b: weights f32 [256][512] -> f16 transposed [512][256] -----
__global__ __launch_bounds__(256) void k_convert_w(
    const float* __restrict__ Wk, const float* __restrict__ Wv,
    const float* __restrict__ Wq, const float* __restrict__ Wr,
    unsigned short* __restrict__ WT) {
  int o = blockIdx.x * 256 + threadIdx.x;  // 0..524287
  int mat = o >> 17, rem = o & 131071;
  int n = rem >> 8, k = rem & 255;
  const float* W = mat == 0 ? Wk : mat == 1 ? Wv : mat == 2 ? Wq : Wr;
  WT[o] = f2h(W[k * 512 + n]);
}

// ---------------- K2: 4 projection GEMMs, f16 MFMA ----------------
__global__ __launch_bounds__(256) void k_gemm(
    const unsigned short* __restrict__ Ab, const unsigned short* __restrict__ WT,
    const float* __restrict__ bk, const float* __restrict__ bv,
    const float* __restrict__ bq, const float* __restrict__ br,
    unsigned short* __restrict__ Kb, unsigned short* __restrict__ Vh,
    unsigned short* __restrict__ Qb, unsigned short* __restrict__ Rh) {
  const float CS = 0.70710678118654752f * 1.44269504088896341f;
  int b = blockIdx.x;
  int id2 = (b & 7) * 256 + (b >> 3);       // XCD c owns id2 in [c*256,(c+1)*256)
  int nx = id2 & 3, my = (id2 >> 2) & 127, mat = id2 >> 9;
  const unsigned short* A = Ab + (size_t)(mat == 3 ? 2 : mat) * 4194304u;
  const unsigned short* Wm = WT + mat * 131072;
  const float* bias = mat == 0 ? bk : mat == 1 ? bv : mat == 2 ? bq : br;
  unsigned short* C = mat == 0 ? Kb : mat == 1 ? Vh : mat == 2 ? Qb : Rh;
  __shared__ unsigned short As[4096];  // [128][32]
  __shared__ unsigned short Bs[4096];  // [128 n][32 k]
  int m0 = my * 128, n0 = nx * 128;
  int tid = threadIdx.x, lane = tid & 63, w = tid >> 6;
  int wm = w >> 1, wn = w & 1, q = lane & 15, hi = lane >> 4;
  f32x4 acc[4][4];
#pragma unroll
  for (int i = 0; i < 4; ++i)
#pragma unroll
    for (int j = 0; j < 4; ++j) acc[i][j] = f32x4{0.f, 0.f, 0.f, 0.f};

  const unsigned short* gA = A + (m0 + (tid >> 2)) * 256 + (tid & 3) * 8;
  const unsigned short* gB = Wm + (n0 + (tid >> 2)) * 256 + (tid & 3) * 8;

  for (int kt = 0; kt < 8; ++kt) {
    __syncthreads();
    GLDS16(gA, &As[tid * 8]);
    GLDS16(gA + 64 * 256, &As[2048 + tid * 8]);
    GLDS16(gB, &Bs[tid * 8]);
    GLDS16(gB + 64 * 256, &Bs[2048 + tid * 8]);
    gA += 32; gB += 32;
    __syncthreads();
    f16x8 af[4], bf[4];
#pragma unroll
    for (int i = 0; i < 4; ++i)
      af[i] = *(const f16x8*)&As[(wm * 64 + i * 16 + q) * 32 + hi * 8];
#pragma unroll
    for (int j = 0; j < 4; ++j)
      bf[j] = *(const f16x8*)&Bs[(wn * 64 + j * 16 + q) * 32 + hi * 8];
#pragma unroll
    for (int i = 0; i < 4; ++i)
#pragma unroll
      for (int j = 0; j < 4; ++j)
        acc[i][j] = __builtin_amdgcn_mfma_f32_16x16x32_f16(af[i], bf[j], acc[i][j], 0, 0, 0);
  }

  float scale = (mat == 2) ? CS : 1.0f;
#pragma unroll
  for (int j = 0; j < 4; ++j) {
    int col = n0 + wn * 64 + j * 16 + q;
    float bs = bias[col];
#pragma unroll
    for (int i = 0; i < 4; ++i) {
      int rb = m0 + wm * 64 + i * 16 + 4 * hi;
#pragma unroll
      for (int r = 0; r < 4; ++r) {
        float v = (acc[i][j][r] + bs) * scale;
        C[(rb + r) * 512 + col] = f2h(v);
      }
    }
  }
}

// -------- K2b: V transpose per group: Vt[g][d][s] = Vh(flat)[g][s][d] -------
__global__ __launch_bounds__(256) void k_vt(
    const unsigned short* __restrict__ Vh, unsigned short* __restrict__ Vt) {
  int t0 = blockIdx.x * 256 + threadIdx.x;  // 0..524287
#pragma unroll
  for (int it = 0; it < 2; ++it) {
    int c = t0 + it * 524288;  // chunk id 0..1048575 : 8 shorts each
    int s8 = c & 127, d = (c >> 7) & 31, g = c >> 12;  // g in [0,256)
    const unsigned short* src = Vh + g * 32768 + s8 * 256 + d;
    us8 v;
#pragma unroll
    for (int i = 0; i < 8; ++i) v[i] = src[i * 32];
    *(us8*)&Vt[g * 32768 + d * 1024 + s8 * 8] = v;
  }
}

// ---------------- K3: attention + residual + relu (32x32 MFMA, T12) --------
// One 1024-thread block per group. K+V staged once into LDS (swizzled).
// Swapped QK (mfma(K,Q), C-init=-24) -> lane holds P[q][k-rows]; PV B-operand
// built IN-REGISTER via cvt_pkrtz + v_permlane32_swap_b32 (no P LDS traffic,
// no wave barriers). l via fdot2, one shfl_xor(32) at end.
__global__ __launch_bounds__(1024) void k_attn(
    const unsigned short* __restrict__ Kb, const unsigned short* __restrict__ Vt,
    const unsigned short* __restrict__ Qb, const unsigned short* __restrict__ Rh,
    float* __restrict__ out) {
  __shared__ __align__(16) char Ks[65536];  // [1024 s][32 d] swizzled (XOR bits4-6 <- (s>>1)&7)
  __shared__ __align__(16) char Vs[65536];  // [32 d][1024 s] swizzled (XOR bits4-6 <- d&7)

  int p = blockIdx.x;                 // 256 blocks, 1 per group
  int g = (p & 7) * 32 + (p >> 3);    // XCD-bijective
  int tid = threadIdx.x, lane = tid & 63, wid = tid >> 6;
  int q = lane & 31, h2 = lane >> 5;

  // ---- stage K and V (64KB each), inverse-swizzled global source ----
  const char* Ksrc = (const char*)Kb + (size_t)g * 65536;
  const char* Vsrc = (const char*)Vt + (size_t)g * 65536;
#pragma unroll
  for (int r = 0; r < 4; ++r) {
    int d = tid * 16 + r * 16384;
    GLDS16(Ksrc + (d ^ (((d >> 7) & 7) << 4)), Ks + d);
    GLDS16(Vsrc + (d ^ (((d >> 11) & 7) << 4)), Vs + d);
  }

  // Q fragments: B[k=kh*16+8h2+j][q] = Q[qrow][dk]; 2 per qt
  const unsigned short* Qg = Qb + g * 32768 + wid * 2048;
  f16x8 qf[2][2];
#pragma unroll
  for (int qt = 0; qt < 2; ++qt)
#pragma unroll
    for (int kh = 0; kh < 2; ++kh)
      qf[qt][kh] = *(const f16x8*)&Qg[(qt * 32 + q) * 32 + kh * 16 + h2 * 8];

  // LDS read bases (swizzle folded; kh/kb terms XOR-composed, R9 rule)
  int kbase = (q * 64 + h2 * 16) ^ (((q >> 1) & 7) << 4);   // ^ (kh<<5), + kv*4096 + blk*2048
  int vbase = (q * 2048 + h2 * 16) ^ ((q & 7) << 4);        // ^ (kb<<5), + kv*128

  const f16x2 ones2 = {(_Float16)1.0f, (_Float16)1.0f};
  f32x16 o[2];
#pragma unroll
  for (int i = 0; i < 16; ++i) { o[0][i] = 0.f; o[1][i] = 0.f; }
  float lacc[2] = {0.f, 0.f};
  f32x16 neg24;
#pragma unroll
  for (int i = 0; i < 16; ++i) neg24[i] = -24.f;

  __syncthreads();  // staging complete

  for (int kv = 0; kv < 16; ++kv) {
#pragma unroll
    for (int blk = 0; blk < 2; ++blk) {
      // K fragments for krows s in [kv*64+blk*32, +32): kh = dk half
      f16x8 kf0 = *(const f16x8*)(Ks + (kbase ^ 0)  + kv * 4096 + blk * 2048);
      f16x8 kf1 = *(const f16x8*)(Ks + (kbase ^ 32) + kv * 4096 + blk * 2048);
      // V fragments for s 16-blocks kb = 2blk, 2blk+1
      f16x8 vf0 = *(const f16x8*)(Vs + ((vbase ^ ((2 * blk) << 5)) + kv * 128));
      f16x8 vf1 = *(const f16x8*)(Vs + ((vbase ^ ((2 * blk + 1) << 5)) + kv * 128));

#pragma unroll
      for (int qt = 0; qt < 2; ++qt) {
        f32x16 st;
        __builtin_amdgcn_s_setprio(1);
        st = __builtin_amdgcn_mfma_f32_32x32x16_f16(kf0, qf[qt][0], neg24, 0, 0, 0);
        st = __builtin_amdgcn_mfma_f32_32x32x16_f16(kf1, qf[qt][1], st, 0, 0, 0);
        __builtin_amdgcn_s_setprio(0);

        // p = exp2(st); pack pairs (reg 2m, 2m+1)
        unsigned int w[8];
#pragma unroll
        for (int m = 0; m < 8; ++m) {
          float p0 = __builtin_amdgcn_exp2f(st[2 * m]);
          float p1 = __builtin_amdgcn_exp2f(st[2 * m + 1]);
          w[m] = __builtin_bit_cast(unsigned int, __builtin_amdgcn_cvt_pkrtz(p0, p1));
        }
        // l accumulation (own 16 values; halves merged at end)
#pragma unroll
        for (int m = 0; m < 8; ++m)
          lacc[qt] = __builtin_amdgcn_fdot2(__builtin_bit_cast(f16x2, w[m]), ones2, lacc[qt], false);

        // in-register P^T fragments: swap halves (A'=[A_lo,B_lo], B'=[A_hi,B_hi])
        unsigned int a0 = w[0], a2 = w[2], a1 = w[1], a3 = w[3];
        unsigned int b0 = w[4], b2 = w[6], b1 = w[5], b3 = w[7];
        asm("v_permlane32_swap_b32 %0, %1" : "+v"(a0), "+v"(a2));
        asm("v_permlane32_swap_b32 %0, %1" : "+v"(a1), "+v"(a3));
        asm("v_permlane32_swap_b32 %0, %1" : "+v"(b0), "+v"(b2));
        asm("v_permlane32_swap_b32 %0, %1" : "+v"(b1), "+v"(b3));
        f16x8 pb0 = __builtin_bit_cast(f16x8, (u32x4){a0, a1, a2, a3});  // k-block 2blk
        f16x8 pb1 = __builtin_bit_cast(f16x8, (u32x4){b0, b1, b2, b3});  // k-block 2blk+1

        __builtin_amdgcn_s_setprio(1);
        o[qt] = __builtin_amdgcn_mfma_f32_32x32x16_f16(vf0, pb0, o[qt], 0, 0, 0);
        o[qt] = __builtin_amdgcn_mfma_f32_32x32x16_f16(vf1, pb1, o[qt], 0, 0, 0);
        __builtin_amdgcn_s_setprio(0);
      }
    }
  }

  // merge halves: lanes q and q+32 hold complementary k-sums
#pragma unroll
  for (int qt = 0; qt < 2; ++qt)
    lacc[qt] += __shfl_xor(lacc[qt], 32, 64);

#pragma unroll
  for (int qt = 0; qt < 2; ++qt) {
    float iv = 1.0f / lacc[qt];
    int rowoff = g * 32768 + (wid * 64 + qt * 32 + q) * 32;
#pragma unroll
    for (int rg = 0; rg < 4; ++rg) {
      int off = rowoff + rg * 8 + h2 * 4;   // d = (r&3) + 8*rg + 4*h2
      ushort4 rr = *(const ushort4*)&Rh[off];
      float4 ov;
      ov.x = fmaxf(h2f(rr.x) + o[qt][4 * rg + 0] * iv, 0.f);
      ov.y = fmaxf(h2f(rr.y) + o[qt][4 * rg + 1] * iv, 0.f);
      ov.z = fmaxf(h2f(rr.z) + o[qt][4 * rg + 2] * iv, 0.f);
      ov.w = fmaxf(h2f(rr.w) + o[qt][4 * rg + 3] * iv, 0.f);
      *(float4*)&out[off] = ov;
    }
  }
}

extern "C" void kernel_launch(void* const* d_in, const int* in_sizes, int n_in,
                              void* d_out, int out_size, void* d_ws, size_t ws_size,
                              hipStream_t stream) {
  const float* key0 = (const float*)d_in[0];
  const float* value0 = (const float*)d_in[1];
  const float* query0 = (const float*)d_in[2];
  const float* Wk = (const float*)d_in[3];
  const float* bk = (const float*)d_in[4];
  const float* Wv = (const float*)d_in[5];
  const float* bv = (const float*)d_in[6];
  const float* Wq = (const float*)d_in[7];
  const float* bq = (const float*)d_in[8];
  const float* Wr = (const float*)d_in[9];
  const float* br = (const float*)d_in[10];
  float* out = (float*)d_out;
  char* ws = (char*)d_ws;
  unsigned short* Kb = (unsigned short*)(ws);              // 16 MB f16 [16384,512]
  unsigned short* Vt = (unsigned short*)(ws + 16777216);   // 16 MB f16 [256][32][1024]
  unsigned short* Qb = (unsigned short*)(ws + 33554432);   // 16 MB f16 (pre-scaled)
  unsigned short* Rh = (unsigned short*)(ws + 50331648);   // 16 MB f16 [16384,512]
  unsigned short* Ab = (unsigned short*)(ws + 67108864);   // 24 MB f16 [3][16384,256]
  unsigned short* WT = (unsigned short*)(ws + 92274688);   // 1 MB f16 [4][512][256]
  unsigned short* Vh = (unsigned short*)(ws + 93323264);   // 16 MB f16 [16384,512]

  k_convert_in<<<dim3(1024, 3), dim3(256), 0, stream>>>(key0, value0, query0, Ab);
  k_convert_w<<<dim3(2048), dim3(256), 0, stream>>>(Wk, Wv, Wq, Wr, WT);
  k_gemm<<<dim3(2048), dim3(256), 0, stream>>>(Ab, WT, bk, bv, bq, br, Kb, Vh, Qb, Rh);
  k_vt<<<dim3(2048), dim3(256), 0, stream>>>(Vh, Vt);
  k_attn<<<dim3(256), dim3(1024), 0, stream>>>(Kb, Vt, Qb, Rh, out);
}

// Round 13
// 129.026 us; speedup vs baseline: 1.3618x; 1.0509x over previous
//
#include <hip/hip_runtime.h>
#include <hip/hip_bf16.h>

typedef _Float16 f16x8 __attribute__((ext_vector_type(8)));
typedef _Float16 f16x2 __attribute__((ext_vector_type(2)));
typedef float f32x4 __attribute__((ext_vector_type(4)));
typedef float f32x16 __attribute__((ext_vector_type(16)));
typedef unsigned int u32x4 __attribute__((ext_vector_type(4)));
typedef unsigned short us8 __attribute__((ext_vector_type(8)));

#define GLDS16(gp, lp)                                                        \
  __builtin_amdgcn_global_load_lds(                                           \
      (const __attribute__((address_space(1))) void*)(gp),                    \
      (__attribute__((address_space(3))) void*)(lp), 16, 0, 0)

__device__ __forceinline__ unsigned short f2h(float f) {
  _Float16 h = (_Float16)f;
  return __builtin_bit_cast(unsigned short, h);
}
__device__ __forceinline__ float h2f(unsigned short u) {
  return (float)__builtin_bit_cast(_Float16, u);
}
__device__ __forceinline__ unsigned int pk2(float a, float b) {
  return __builtin_bit_cast(unsigned int, __builtin_amdgcn_cvt_pkrtz(a, b));
}

// ------------- K1b: weights f32 [256][512] -> f16 transposed [512][256] -----
__global__ __launch_bounds__(256) void k_convert_w(
    const float* __restrict__ Wk, const float* __restrict__ Wv,
    const float* __restrict__ Wq, const float* __restrict__ Wr,
    unsigned short* __restrict__ WT) {
  int o = blockIdx.x * 256 + threadIdx.x;  // 0..524287
  int mat = o >> 17, rem = o & 131071;
  int n = rem >> 8, k = rem & 255;
  const float* W = mat == 0 ? Wk : mat == 1 ? Wv : mat == 2 ? Wq : Wr;
  WT[o] = f2h(W[k * 512 + n]);
}

// ---------------- K2: 4 projection GEMMs, f16 MFMA, 2-phase dbuf -----------
// Reads f32 activations directly (fuses the f32->f16 convert via reg-staging).
// C[16384,512] = A[16384,256] * W[256,512] + bias ; mat: 0=K,1=V,2=Q(scaled),3=R
__global__ __launch_bounds__(256) void k_gemm(
    const float* __restrict__ k0, const float* __restrict__ v0,
    const float* __restrict__ q0, const unsigned short* __restrict__ WT,
    const float* __restrict__ bk, const float* __restrict__ bv,
    const float* __restrict__ bq, const float* __restrict__ br,
    unsigned short* __restrict__ Kb, unsigned short* __restrict__ Vh,
    unsigned short* __restrict__ Qb, unsigned short* __restrict__ Rh) {
  const float CS = 0.70710678118654752f * 1.44269504088896341f;
  int b = blockIdx.x;
  int id2 = (b & 7) * 256 + (b >> 3);       // XCD c owns id2 in [c*256,(c+1)*256)
  int nx = id2 & 3, my = (id2 >> 2) & 127, mat = id2 >> 9;
  const float* A = mat == 0 ? k0 : mat == 1 ? v0 : q0;  // mat 3 shares query0
  const unsigned short* Wm = WT + mat * 131072;
  const float* bias = mat == 0 ? bk : mat == 1 ? bv : mat == 2 ? bq : br;
  unsigned short* C = mat == 0 ? Kb : mat == 1 ? Vh : mat == 2 ? Qb : Rh;
  __shared__ unsigned short As[2][4096];  // [128][32] f16, double-buffered
  __shared__ unsigned short Bs[2][4096];  // [128 n][32 k] (W^T tile)
  int m0 = my * 128, n0 = nx * 128;
  int tid = threadIdx.x, lane = tid & 63, w = tid >> 6;
  int wm = w >> 1, wn = w & 1, q = lane & 15, hi = lane >> 4;
  f32x4 acc[4][4];
#pragma unroll
  for (int i = 0; i < 4; ++i)
#pragma unroll
    for (int j = 0; j < 4; ++j) acc[i][j] = f32x4{0.f, 0.f, 0.f, 0.f};

  const float* gA = A + (m0 + (tid >> 1)) * 256 + (tid & 1) * 16;  // f32 row-half
  const unsigned short* gB = Wm + (n0 + (tid >> 2)) * 256 + (tid & 3) * 8;
  int aoff = (tid >> 1) * 32 + (tid & 1) * 16;  // As element offset

  // ---- prologue: stage tile 0 ----
  float4 ar[4];
#pragma unroll
  for (int i = 0; i < 4; ++i) ar[i] = *(const float4*)(gA + i * 4);
  GLDS16(gB, &Bs[0][tid * 8]);
  GLDS16(gB + 64 * 256, &Bs[0][2048 + tid * 8]);
  {
    u32x4 w0 = {pk2(ar[0].x, ar[0].y), pk2(ar[0].z, ar[0].w),
                pk2(ar[1].x, ar[1].y), pk2(ar[1].z, ar[1].w)};
    u32x4 w1 = {pk2(ar[2].x, ar[2].y), pk2(ar[2].z, ar[2].w),
                pk2(ar[3].x, ar[3].y), pk2(ar[3].z, ar[3].w)};
    *(u32x4*)&As[0][aoff] = w0;
    *(u32x4*)&As[0][aoff + 8] = w1;
  }
  __syncthreads();

  for (int kt = 0; kt < 8; ++kt) {
    int cur = kt & 1, nxt = cur ^ 1;
    if (kt < 7) {  // issue next-tile loads BEFORE compute (latency overlaps MFMA)
#pragma unroll
      for (int i = 0; i < 4; ++i)
        ar[i] = *(const float4*)(gA + (kt + 1) * 32 + i * 4);
      GLDS16(gB + (kt + 1) * 32, &Bs[nxt][tid * 8]);
      GLDS16(gB + (kt + 1) * 32 + 64 * 256, &Bs[nxt][2048 + tid * 8]);
    }
    f16x8 af[4], bf[4];
#pragma unroll
    for (int i = 0; i < 4; ++i)
      af[i] = *(const f16x8*)&As[cur][(wm * 64 + i * 16 + q) * 32 + hi * 8];
#pragma unroll
    for (int j = 0; j < 4; ++j)
      bf[j] = *(const f16x8*)&Bs[cur][(wn * 64 + j * 16 + q) * 32 + hi * 8];
#pragma unroll
    for (int i = 0; i < 4; ++i)
#pragma unroll
      for (int j = 0; j < 4; ++j)
        acc[i][j] = __builtin_amdgcn_mfma_f32_16x16x32_f16(af[i], bf[j], acc[i][j], 0, 0, 0);
    if (kt < 7) {  // A arrived under the MFMAs; convert + park in next buffer
      u32x4 w0 = {pk2(ar[0].x, ar[0].y), pk2(ar[0].z, ar[0].w),
                  pk2(ar[1].x, ar[1].y), pk2(ar[1].z, ar[1].w)};
      u32x4 w1 = {pk2(ar[2].x, ar[2].y), pk2(ar[2].z, ar[2].w),
                  pk2(ar[3].x, ar[3].y), pk2(ar[3].z, ar[3].w)};
      *(u32x4*)&As[nxt][aoff] = w0;
      *(u32x4*)&As[nxt][aoff + 8] = w1;
    }
    __syncthreads();
  }

  float scale = (mat == 2) ? CS : 1.0f;
#pragma unroll
  for (int j = 0; j < 4; ++j) {
    int col = n0 + wn * 64 + j * 16 + q;
    float bs = bias[col];
#pragma unroll
    for (int i = 0; i < 4; ++i) {
      int rb = m0 + wm * 64 + i * 16 + 4 * hi;
#pragma unroll
      for (int r = 0; r < 4; ++r) {
        float v = (acc[i][j][r] + bs) * scale;
        C[(rb + r) * 512 + col] = f2h(v);
      }
    }
  }
}

// -------- K2b: V transpose per group: Vt[g][d][s] = Vh(flat)[g][s][d] -------
__global__ __launch_bounds__(256) void k_vt(
    const unsigned short* __restrict__ Vh, unsigned short* __restrict__ Vt) {
  int t0 = blockIdx.x * 256 + threadIdx.x;  // 0..524287
#pragma unroll
  for (int it = 0; it < 2; ++it) {
    int c = t0 + it * 524288;  // chunk id 0..1048575 : 8 shorts each
    int s8 = c & 127, d = (c >> 7) & 31, g = c >> 12;  // g in [0,256)
    const unsigned short* src = Vh + g * 32768 + s8 * 256 + d;
    us8 v;
#pragma unroll
    for (int i = 0; i < 8; ++i) v[i] = src[i * 32];
    *(us8*)&Vt[g * 32768 + d * 1024 + s8 * 8] = v;
  }
}

// ---------------- K3: attention + residual + relu (32x32 MFMA, T12) --------
__global__ __launch_bounds__(1024) void k_attn(
    const unsigned short* __restrict__ Kb, const unsigned short* __restrict__ Vt,
    const unsigned short* __restrict__ Qb, const unsigned short* __restrict__ Rh,
    float* __restrict__ out) {
  __shared__ __align__(16) char Ks[65536];  // [1024 s][32 d] swizzled (XOR bits4-6 <- (s>>1)&7)
  __shared__ __align__(16) char Vs[65536];  // [32 d][1024 s] swizzled (XOR bits4-6 <- d&7)

  int p = blockIdx.x;                 // 256 blocks, 1 per group
  int g = (p & 7) * 32 + (p >> 3);    // XCD-bijective
  int tid = threadIdx.x, lane = tid & 63, wid = tid >> 6;
  int q = lane & 31, h2 = lane >> 5;

  const char* Ksrc = (const char*)Kb + (size_t)g * 65536;
  const char* Vsrc = (const char*)Vt + (size_t)g * 65536;
#pragma unroll
  for (int r = 0; r < 4; ++r) {
    int d = tid * 16 + r * 16384;
    GLDS16(Ksrc + (d ^ (((d >> 7) & 7) << 4)), Ks + d);
    GLDS16(Vsrc + (d ^ (((d >> 11) & 7) << 4)), Vs + d);
  }

  const unsigned short* Qg = Qb + g * 32768 + wid * 2048;
  f16x8 qf[2][2];
#pragma unroll
  for (int qt = 0; qt < 2; ++qt)
#pragma unroll
    for (int kh = 0; kh < 2; ++kh)
      qf[qt][kh] = *(const f16x8*)&Qg[(qt * 32 + q) * 32 + kh * 16 + h2 * 8];

  int kbase = (q * 64 + h2 * 16) ^ (((q >> 1) & 7) << 4);   // ^ (kh<<5), + kv*4096 + blk*2048
  int vbase = (q * 2048 + h2 * 16) ^ ((q & 7) << 4);        // ^ (kb<<5), + kv*128

  const f16x2 ones2 = {(_Float16)1.0f, (_Float16)1.0f};
  f32x16 o[2];
#pragma unroll
  for (int i = 0; i < 16; ++i) { o[0][i] = 0.f; o[1][i] = 0.f; }
  float lacc[2] = {0.f, 0.f};
  f32x16 neg24;
#pragma unroll
  for (int i = 0; i < 16; ++i) neg24[i] = -24.f;

  __syncthreads();  // staging complete

  for (int kv = 0; kv < 16; ++kv) {
#pragma unroll
    for (int blk = 0; blk < 2; ++blk) {
      f16x8 kf0 = *(const f16x8*)(Ks + (kbase ^ 0)  + kv * 4096 + blk * 2048);
      f16x8 kf1 = *(const f16x8*)(Ks + (kbase ^ 32) + kv * 4096 + blk * 2048);
      f16x8 vf0 = *(const f16x8*)(Vs + ((vbase ^ ((2 * blk) << 5)) + kv * 128));
      f16x8 vf1 = *(const f16x8*)(Vs + ((vbase ^ ((2 * blk + 1) << 5)) + kv * 128));

#pragma unroll
      for (int qt = 0; qt < 2; ++qt) {
        f32x16 st;
        __builtin_amdgcn_s_setprio(1);
        st = __builtin_amdgcn_mfma_f32_32x32x16_f16(kf0, qf[qt][0], neg24, 0, 0, 0);
        st = __builtin_amdgcn_mfma_f32_32x32x16_f16(kf1, qf[qt][1], st, 0, 0, 0);
        __builtin_amdgcn_s_setprio(0);

        unsigned int w[8];
#pragma unroll
        for (int m = 0; m < 8; ++m) {
          float p0 = __builtin_amdgcn_exp2f(st[2 * m]);
          float p1 = __builtin_amdgcn_exp2f(st[2 * m + 1]);
          w[m] = pk2(p0, p1);
        }
#pragma unroll
        for (int m = 0; m < 8; ++m)
          lacc[qt] = __builtin_amdgcn_fdot2(__builtin_bit_cast(f16x2, w[m]), ones2, lacc[qt], false);

        unsigned int a0 = w[0], a2 = w[2], a1 = w[1], a3 = w[3];
        unsigned int b0 = w[4], b2 = w[6], b1 = w[5], b3 = w[7];
        asm("v_permlane32_swap_b32 %0, %1" : "+v"(a0), "+v"(a2));
        asm("v_permlane32_swap_b32 %0, %1" : "+v"(a1), "+v"(a3));
        asm("v_permlane32_swap_b32 %0, %1" : "+v"(b0), "+v"(b2));
        asm("v_permlane32_swap_b32 %0, %1" : "+v"(b1), "+v"(b3));
        f16x8 pb0 = __builtin_bit_cast(f16x8, (u32x4){a0, a1, a2, a3});
        f16x8 pb1 = __builtin_bit_cast(f16x8, (u32x4){b0, b1, b2, b3});

        __builtin_amdgcn_s_setprio(1);
        o[qt] = __builtin_amdgcn_mfma_f32_32x32x16_f16(vf0, pb0, o[qt], 0, 0, 0);
        o[qt] = __builtin_amdgcn_mfma_f32_32x32x16_f16(vf1, pb1, o[qt], 0, 0, 0);
        __builtin_amdgcn_s_setprio(0);
      }
    }
  }

#pragma unroll
  for (int qt = 0; qt < 2; ++qt)
    lacc[qt] += __shfl_xor(lacc[qt], 32, 64);

#pragma unroll
  for (int qt = 0; qt < 2; ++qt) {
    float iv = 1.0f / lacc[qt];
    int rowoff = g * 32768 + (wid * 64 + qt * 32 + q) * 32;
#pragma unroll
    for (int rg = 0; rg < 4; ++rg) {
      int off = rowoff + rg * 8 + h2 * 4;   // d = (r&3) + 8*rg + 4*h2
      ushort4 rr = *(const ushort4*)&Rh[off];
      float4 ov;
      ov.x = fmaxf(h2f(rr.x) + o[qt][4 * rg + 0] * iv, 0.f);
      ov.y = fmaxf(h2f(rr.y) + o[qt][4 * rg + 1] * iv, 0.f);
      ov.z = fmaxf(h2f(rr.z) + o[qt][4 * rg + 2] * iv, 0.f);
      ov.w = fmaxf(h2f(rr.w) + o[qt][4 * rg + 3] * iv, 0.f);
      *(float4*)&out[off] = ov;
    }
  }
}

extern "C" void kernel_launch(void* const* d_in, const int* in_sizes, int n_in,
                              void* d_out, int out_size, void* d_ws, size_t ws_size,
                              hipStream_t stream) {
  const float* key0 = (const float*)d_in[0];
  const float* value0 = (const float*)d_in[1];
  const float* query0 = (const float*)d_in[2];
  const float* Wk = (const float*)d_in[3];
  const float* bk = (const float*)d_in[4];
  const float* Wv = (const float*)d_in[5];
  const float* bv = (const float*)d_in[6];
  const float* Wq = (const float*)d_in[7];
  const float* bq = (const float*)d_in[8];
  const float* Wr = (const float*)d_in[9];
  const float* br = (const float*)d_in[10];
  float* out = (float*)d_out;
  char* ws = (char*)d_ws;
  unsigned short* Kb = (unsigned short*)(ws);              // 16 MB f16 [16384,512]
  unsigned short* Vt = (unsigned short*)(ws + 16777216);   // 16 MB f16 [256][32][1024]
  unsigned short* Qb = (unsigned short*)(ws + 33554432);   // 16 MB f16 (pre-scaled)
  unsigned short* Rh = (unsigned short*)(ws + 50331648);   // 16 MB f16 [16384,512]
  unsigned short* WT = (unsigned short*)(ws + 92274688);   // 1 MB f16 [4][512][256]
  unsigned short* Vh = (unsigned short*)(ws + 93323264);   // 16 MB f16 [16384,512]

  k_convert_w<<<dim3(2048), dim3(256), 0, stream>>>(Wk, Wv, Wq, Wr, WT);
  k_gemm<<<dim3(2048), dim3(256), 0, stream>>>(key0, value0, query0, WT,
                                               bk, bv, bq, br, Kb, Vh, Qb, Rh);
  k_vt<<<dim3(2048), dim3(256), 0, stream>>>(Vh, Vt);
  k_attn<<<dim3(256), dim3(1024), 0, stream>>>(Kb, Vt, Qb, Rh, out);
}